// Round 7
// baseline (146.876 us; speedup 1.0000x reference)
//
#include <hip/hip_runtime.h>
#include <stdint.h>
#include <stddef.h>

typedef __attribute__((ext_vector_type(8))) short short8;
typedef __attribute__((ext_vector_type(4))) float f32x4;
typedef __attribute__((ext_vector_type(16))) float f32x16;
typedef __attribute__((ext_vector_type(4))) unsigned int uint4v;

#define MFMA16(a, b, c) __builtin_amdgcn_mfma_f32_16x16x32_bf16((a), (b), (c), 0, 0, 0)
#define MFMA32(a, b, c) __builtin_amdgcn_mfma_f32_32x32x16_bf16((a), (b), (c), 0, 0, 0)

__device__ __forceinline__ unsigned short f2bf(float f) {
  unsigned int u = __builtin_bit_cast(unsigned int, f);
  u += 0x7fffu + ((u >> 16) & 1u);
  return (unsigned short)(u >> 16);
}

// validated integer RNE pack (round 5)
__device__ __forceinline__ unsigned int pk2(float lo, float hi) {
  return (unsigned int)f2bf(lo) | ((unsigned int)f2bf(hi) << 16);
}

__device__ __forceinline__ short8 mk8(const unsigned short* p) {
  return *(const short8*)p;
}

// cross-half (lane^32) reductions
__device__ __forceinline__ float redmax32(float v) {
  return fmaxf(v, __shfl_xor(v, 32));
}
__device__ __forceinline__ float redsum32(float v) {
  return v + __shfl_xor(v, 32);
}

__device__ __forceinline__ f32x16 zero16() {
  f32x16 v;
#pragma unroll
  for (int i = 0; i < 16; ++i) v[i] = 0.f;
  return v;
}

// swizzled offset into a [rows][40]-half LDS tile holding 32 data cols.
__device__ __forceinline__ int swz40(int row, int c) {
  return row * 40 + ((((c >> 3) ^ (row >> 3)) & 3) << 3) + (c & 7);
}

// ---------------- kernel 0: cast weights to bf16 ----------------
__global__ __launch_bounds__(256) void k_prep(const float* __restrict__ wq,
                                              const float* __restrict__ wo,
                                              unsigned short* __restrict__ wq_bf,
                                              unsigned short* __restrict__ wo_bf) {
  int i = blockIdx.x * 256 + threadIdx.x;
  if (i < 98304) wq_bf[i] = f2bf(wq[i]);
  if (i < 32768) wo_bf[i] = f2bf(wo[i]);
}

// ---------------- kernel 1: fused RMSNorm + QKV GEMM ----------------
// Stage bf16(x*g), accumulate sum(x^2) during staging, apply
// r = rsqrt(mean+eps) to the accumulator at the epilogue.
// Output layouts:
//   Q, K: [bh][p][d]   buf + (bh*4096 + p)*32 + d
//   V:    [bh][d][p']  p' = sigma(p) within each 16-block (swap bits 2,3)
__global__ __launch_bounds__(256) void k_qkv(const float* __restrict__ x,
                                             const float* __restrict__ g,
                                             const unsigned short* __restrict__ wq_bf,
                                             unsigned short* __restrict__ qbuf,
                                             unsigned short* __restrict__ kbuf,
                                             unsigned short* __restrict__ vbuf) {
  int bid = blockIdx.x;            // 768 = 4b * 6ot * 32pt
  int b = bid / 192;
  int rem = bid % 192;
  int ot = rem / 32;
  int pt = rem % 32;
  int o0 = ot * 64, p0 = pt * 128;

  __shared__ unsigned short xnT[128 * 40];
  __shared__ float sq[2][128];
  __shared__ float rl[128];

  int t = threadIdx.x;
  int lane = t & 63, w = t >> 6;
  int lr = lane & 15, lg = lane >> 4;
  int pl = t & 127, ch = t >> 7;

  const float* xb = x + (size_t)b * 256 * 4096;
  const unsigned short* wqrow = wq_bf + (size_t)(o0 + w * 16 + lr) * 256;

  f32x4 acc[8];
  f32x4 z = {0.f, 0.f, 0.f, 0.f};
#pragma unroll
  for (int i = 0; i < 8; ++i) acc[i] = z;
  float sacc = 0.f;

  for (int c0 = 0; c0 < 256; c0 += 32) {
    __syncthreads();
#pragma unroll
    for (int i = 0; i < 8; ++i) {
      int c = ch * 16 + i * 2;
      float v0 = xb[(size_t)(c0 + c) * 4096 + p0 + pl];
      float v1 = xb[(size_t)(c0 + c + 1) * 4096 + p0 + pl];
      sacc += v0 * v0 + v1 * v1;
      *(unsigned int*)&xnT[swz40(pl, c)] = pk2(v0 * g[c0 + c], v1 * g[c0 + c + 1]);
    }
    __syncthreads();
    short8 af = mk8(wqrow + c0 + lg * 8);
#pragma unroll
    for (int pt16 = 0; pt16 < 8; ++pt16) {
      short8 bf = mk8(&xnT[swz40(pt16 * 16 + lr, lg * 8)]);
      acc[pt16] = MFMA16(af, bf, acc[pt16]);
    }
  }

  sq[ch][pl] = sacc;
  __syncthreads();
  if (t < 128) rl[t] = rsqrtf((sq[0][t] + sq[1][t]) * (1.0f / 256.0f) + 1e-12f);
  __syncthreads();

  int obase = o0 + w * 16 + lg * 4;          // multiple of 4
  if (obase < 256) {
    int isK = obase >= 128;
    int oh = obase - (isK ? 128 : 0);
    int h = oh >> 5, d0 = oh & 31;
    unsigned short* dst = (isK ? kbuf : qbuf) + ((size_t)(b * 4 + h) * 4096) * 32;
#pragma unroll
    for (int pt16 = 0; pt16 < 8; ++pt16) {
      int p = p0 + pt16 * 16 + lr;
      float rr = rl[pt16 * 16 + lr];
      unsigned int u0 = pk2(acc[pt16][0] * rr, acc[pt16][1] * rr);
      unsigned int u1 = pk2(acc[pt16][2] * rr, acc[pt16][3] * rr);
      uint2 uu = {u0, u1};
      *(uint2*)(dst + (size_t)p * 32 + d0) = uu;
    }
  } else {
    int oh = obase - 256;
    int h = oh >> 5, d0 = oh & 31;
    unsigned short* dst = vbuf + ((size_t)(b * 4 + h) * 32) * 4096;
    // sigma: swap bits 2 and 3 of the within-block index (involution)
    int sl = (lr & 3) | ((lr & 4) << 1) | ((lr & 8) >> 1);
#pragma unroll
    for (int pt16 = 0; pt16 < 8; ++pt16) {
      int pp = p0 + pt16 * 16 + sl;
      float rr = rl[pt16 * 16 + lr];
#pragma unroll
      for (int r = 0; r < 4; ++r)
        dst[(size_t)(d0 + r) * 4096 + pp] = f2bf(acc[pt16][r] * rr);
    }
  }
}

// ---------------- kernel 2: flash attention, in-block KV-split x2 ----------------
// grid 512 = 16 bh x 32 q-tiles of 128; 8 waves: wave w = (jhalf w>>2, wq w&3).
// Waves w and w+4 process same 32 q-rows over j halves; merged via LDS.
__device__ __forceinline__ void attn_tile(short8 kf0, short8 kf1, short8 vf0, short8 vf1,
                                          short8 qf0, short8 qf1, const f32x16& z16,
                                          float& m, float& ms, float& lsum, f32x16& oacc) {
  const float cexp = 0.25505654427102996f;  // 32^-0.5 * log2(e)
  f32x16 s = MFMA32(kf0, qf0, z16);
  s = MFMA32(kf1, qf1, s);

  float m0 = fmaxf(fmaxf(s[0], s[1]), fmaxf(s[2], s[3]));
  float m1 = fmaxf(fmaxf(s[4], s[5]), fmaxf(s[6], s[7]));
  float m2 = fmaxf(fmaxf(s[8], s[9]), fmaxf(s[10], s[11]));
  float m3 = fmaxf(fmaxf(s[12], s[13]), fmaxf(s[14], s[15]));
  float pmax = redmax32(fmaxf(fmaxf(m0, m1), fmaxf(m2, m3)));

  // defer-max: rescale only when max grew by >8 exp2-units
  if (!__all(fmaf(pmax, cexp, -ms) <= 8.0f)) {
    float mn = fmaxf(m, pmax);
    float fac = __builtin_amdgcn_exp2f((m - mn) * cexp);
    m = mn;
    ms = mn * cexp;
    lsum *= fac;
#pragma unroll
    for (int i = 0; i < 16; ++i) oacc[i] *= fac;
  }

  float p[16];
#pragma unroll
  for (int i = 0; i < 16; ++i) p[i] = __builtin_amdgcn_exp2f(fmaf(s[i], cexp, -ms));

  float s0 = ((p[0] + p[1]) + (p[2] + p[3])) + ((p[4] + p[5]) + (p[6] + p[7]));
  float s1 = ((p[8] + p[9]) + (p[10] + p[11])) + ((p[12] + p[13]) + (p[14] + p[15]));
  lsum += s0 + s1;

  // Own-lane B-fragments (validated pk2); V stored sigma-permuted to match
  uint4v u0 = {pk2(p[0], p[1]), pk2(p[2], p[3]), pk2(p[4], p[5]), pk2(p[6], p[7])};
  uint4v u1 = {pk2(p[8], p[9]), pk2(p[10], p[11]), pk2(p[12], p[13]), pk2(p[14], p[15])};

  oacc = MFMA32(vf0, __builtin_bit_cast(short8, u0), oacc);
  oacc = MFMA32(vf1, __builtin_bit_cast(short8, u1), oacc);
}

__global__ __launch_bounds__(512) void k_attn(const unsigned short* __restrict__ qbuf,
                                              const unsigned short* __restrict__ kbuf,
                                              const unsigned short* __restrict__ vbuf,
                                              unsigned short* __restrict__ attno) {
  __shared__ float Ol[4][16][64];   // partner O partials
  __shared__ float Ml[4][2][64];    // partner m / lsum

  int bid = blockIdx.x;
  int wid = ((bid & 7) << 6) | (bid >> 3);   // XCD-contiguous (512 % 8 == 0)
  int qt = wid & 31, bh = wid >> 5;
  int t = threadIdx.x, lane = t & 63, w = t >> 6;
  int wq = w & 3, jh = w >> 2;
  int l31 = lane & 31, hi = lane >> 5;
  const float cexp = 0.25505654427102996f;

  const unsigned short* qg = qbuf + (size_t)bh * 4096 * 32;
  const unsigned short* kg = kbuf + (size_t)bh * 4096 * 32;
  const unsigned short* vg = vbuf + (size_t)bh * 32 * 4096;

  int qrow = qt * 128 + wq * 32 + l31;
  short8 qf0 = mk8(qg + (size_t)qrow * 32 + hi * 8);
  short8 qf1 = mk8(qg + (size_t)qrow * 32 + 16 + hi * 8);

  const unsigned short* kl = kg + (size_t)l31 * 32 + hi * 8;    // + j*32
  const unsigned short* vl = vg + (size_t)l31 * 4096 + hi * 8;  // + jbase

  const f32x16 z16 = zero16();
  f32x16 oacc = zero16();
  float m = -1e30f, ms = -2.55e29f, lsum = 0.f;

  int jbase = jh * 2048;
  short8 kf0a = mk8(kl + (size_t)jbase * 32), kf1a = mk8(kl + (size_t)jbase * 32 + 16);
  short8 vf0a = mk8(vl + jbase), vf1a = mk8(vl + jbase + 16);
  short8 kf0b, kf1b, vf0b, vf1b;

  for (int k0 = jbase; k0 < jbase + 2048; k0 += 64) {
    size_t jb = (size_t)(k0 + 32);
    kf0b = mk8(kl + jb * 32);
    kf1b = mk8(kl + jb * 32 + 16);
    vf0b = mk8(vl + jb);
    vf1b = mk8(vl + jb + 16);
    attn_tile(kf0a, kf1a, vf0a, vf1a, qf0, qf1, z16, m, ms, lsum, oacc);

    size_t jn = (size_t)(jbase + ((k0 + 64 - jbase) & 2047));
    kf0a = mk8(kl + jn * 32);
    kf1a = mk8(kl + jn * 32 + 16);
    vf0a = mk8(vl + jn);
    vf1a = mk8(vl + jn + 16);
    attn_tile(kf0b, kf1b, vf0b, vf1b, qf0, qf1, z16, m, ms, lsum, oacc);
  }

  lsum = redsum32(lsum);   // row-total for this j-half

  if (jh == 1) {
#pragma unroll
    for (int i = 0; i < 16; ++i) Ol[wq][i][lane] = oacc[i];
    Ml[wq][0][lane] = m;
    Ml[wq][1][lane] = lsum;
  }
  __syncthreads();
  if (jh == 0) {
    float mb = Ml[wq][0][lane], lb = Ml[wq][1][lane];
    float M = fmaxf(m, mb);
    float fa = __builtin_amdgcn_exp2f((m - M) * cexp);
    float fb = __builtin_amdgcn_exp2f((mb - M) * cexp);
    float rinv = 1.0f / (lsum * fa + lb * fb);
    fa *= rinv;
    fb *= rinv;

    int b = bh >> 2, h = bh & 3;
    unsigned short* ob = attno + ((size_t)b * 4096 + qrow) * 128 + h * 32;
#pragma unroll
    for (int r2 = 0; r2 < 8; ++r2) {
      int reg = r2 * 2;
      int dv = (reg & 3) + 8 * (reg >> 2) + 4 * hi;
      float v0 = oacc[reg] * fa + Ol[wq][reg][lane] * fb;
      float v1 = oacc[reg + 1] * fa + Ol[wq][reg + 1][lane] * fb;
      *(unsigned int*)(ob + dv) = pk2(v0, v1);
    }
  }
}

// ---------------- kernel 3: output projection + bias ----------------
__global__ __launch_bounds__(256) void k_out(const unsigned short* __restrict__ attno,
                                             const unsigned short* __restrict__ wo_bf,
                                             const float* __restrict__ bo,
                                             float* __restrict__ out) {
  int bid = blockIdx.x;
  int b = bid >> 6;
  int p0 = (bid & 63) * 64;
  int t = threadIdx.x, lane = t & 63, w = t >> 6;
  int lr = lane & 15, lg = lane >> 4;

  f32x4 z = {0.f, 0.f, 0.f, 0.f};
  f32x4 acc[4][4];
#pragma unroll
  for (int i = 0; i < 4; ++i)
#pragma unroll
    for (int j = 0; j < 4; ++j) acc[i][j] = z;

  for (int c0 = 0; c0 < 128; c0 += 32) {
    short8 bfr[4];
#pragma unroll
    for (int pt16 = 0; pt16 < 4; ++pt16)
      bfr[pt16] = mk8(attno + (size_t)(b * 4096 + p0 + pt16 * 16 + lr) * 128 + c0 + lg * 8);
#pragma unroll
    for (int ct = 0; ct < 4; ++ct) {
      short8 afr = mk8(wo_bf + (size_t)(w * 64 + ct * 16 + lr) * 128 + c0 + lg * 8);
#pragma unroll
      for (int pt16 = 0; pt16 < 4; ++pt16)
        acc[ct][pt16] = MFMA16(afr, bfr[pt16], acc[ct][pt16]);
    }
  }

#pragma unroll
  for (int ct = 0; ct < 4; ++ct) {
#pragma unroll
    for (int pt16 = 0; pt16 < 4; ++pt16) {
#pragma unroll
      for (int r = 0; r < 4; ++r) {
        int co = w * 64 + ct * 16 + lg * 4 + r;
        int p = p0 + pt16 * 16 + lr;
        out[((size_t)b * 256 + co) * 4096 + p] = acc[ct][pt16][r] + bo[co];
      }
    }
  }
}

extern "C" void kernel_launch(void* const* d_in, const int* in_sizes, int n_in,
                              void* d_out, int out_size, void* d_ws, size_t ws_size,
                              hipStream_t stream) {
  const float* x = (const float*)d_in[0];
  const float* g = (const float*)d_in[1];
  const float* wq = (const float*)d_in[2];
  const float* wo = (const float*)d_in[3];
  const float* bo = (const float*)d_in[4];
  float* out = (float*)d_out;

  char* ws = (char*)d_ws;
  unsigned short* wq_bf = (unsigned short*)(ws + 65536);     // 196608 B
  unsigned short* wo_bf = (unsigned short*)(ws + 262144);    // 65536 B
  unsigned short* qbuf = (unsigned short*)(ws + 327680);     // 4 MiB
  unsigned short* kbuf = (unsigned short*)(ws + 4521984);    // 4 MiB
  unsigned short* vbuf = (unsigned short*)(ws + 8716288);    // 4 MiB
  unsigned short* attno = (unsigned short*)(ws + 12910592);  // 4 MiB

  k_prep<<<dim3(384), dim3(256), 0, stream>>>(wq, wo, wq_bf, wo_bf);
  k_qkv<<<dim3(768), dim3(256), 0, stream>>>(x, g, wq_bf, qbuf, kbuf, vbuf);
  k_attn<<<dim3(512), dim3(512), 0, stream>>>(qbuf, kbuf, vbuf, attno);
  k_out<<<dim3(256), dim3(256), 0, stream>>>(attno, wo_bf, bo, out);
}

// Round 8
// 145.427 us; speedup vs baseline: 1.0100x; 1.0100x over previous
//
#include <hip/hip_runtime.h>
#include <stdint.h>
#include <stddef.h>

typedef __attribute__((ext_vector_type(8))) short short8;
typedef __attribute__((ext_vector_type(4))) float f32x4;
typedef __attribute__((ext_vector_type(16))) float f32x16;
typedef __attribute__((ext_vector_type(4))) unsigned int uint4v;

#define MFMA16(a, b, c) __builtin_amdgcn_mfma_f32_16x16x32_bf16((a), (b), (c), 0, 0, 0)
#define MFMA32(a, b, c) __builtin_amdgcn_mfma_f32_32x32x16_bf16((a), (b), (c), 0, 0, 0)

__device__ __forceinline__ unsigned short f2bf(float f) {
  unsigned int u = __builtin_bit_cast(unsigned int, f);
  u += 0x7fffu + ((u >> 16) & 1u);
  return (unsigned short)(u >> 16);
}

// validated integer RNE pack (round 5) — cold paths
__device__ __forceinline__ unsigned int pk2(float lo, float hi) {
  return (unsigned int)f2bf(lo) | ((unsigned int)f2bf(hi) << 16);
}

// fast round-nearest pack — hot path (positive finite values only)
__device__ __forceinline__ unsigned int pk2rn(float lo, float hi) {
  unsigned int a = __builtin_bit_cast(unsigned int, lo) + 0x8000u;
  unsigned int b = __builtin_bit_cast(unsigned int, hi) + 0x8000u;
  return (b & 0xFFFF0000u) | (a >> 16);
}

__device__ __forceinline__ short8 mk8(const unsigned short* p) {
  return *(const short8*)p;
}

// cross-half (lane^32) max via validated __shfl_xor primitive
__device__ __forceinline__ float redmax32(float v) {
  return fmaxf(v, __shfl_xor(v, 32));
}

__device__ __forceinline__ f32x16 zero16() {
  f32x16 v;
#pragma unroll
  for (int i = 0; i < 16; ++i) v[i] = 0.f;
  return v;
}

// swizzled offset into a [rows][40]-half LDS tile holding 32 data cols.
__device__ __forceinline__ int swz40(int row, int c) {
  return row * 40 + ((((c >> 3) ^ (row >> 3)) & 3) << 3) + (c & 7);
}

// ---------------- kernel 0: cast weights to bf16 ----------------
__global__ __launch_bounds__(256) void k_prep(const float* __restrict__ wq,
                                              const float* __restrict__ wo,
                                              unsigned short* __restrict__ wq_bf,
                                              unsigned short* __restrict__ wo_bf) {
  int i = blockIdx.x * 256 + threadIdx.x;
  if (i < 98304) wq_bf[i] = f2bf(wq[i]);
  if (i < 32768) wo_bf[i] = f2bf(wo[i]);
}

// ---------------- kernel 1: fused RMSNorm + QKV GEMM ----------------
// Stage bf16(x*g), accumulate sum(x^2) during staging, apply
// r = rsqrt(mean+eps) to the accumulator at the epilogue.
// Output layouts:
//   Q, K: [bh][p][d]   buf + (bh*4096 + p)*32 + d
//   V:    [bh][d][p']  p' = sigma(p) within each 16-block (swap bits 2,3)
__global__ __launch_bounds__(256) void k_qkv(const float* __restrict__ x,
                                             const float* __restrict__ g,
                                             const unsigned short* __restrict__ wq_bf,
                                             unsigned short* __restrict__ qbuf,
                                             unsigned short* __restrict__ kbuf,
                                             unsigned short* __restrict__ vbuf) {
  int bid = blockIdx.x;            // 768 = 4b * 6ot * 32pt
  int b = bid / 192;
  int rem = bid % 192;
  int ot = rem / 32;
  int pt = rem % 32;
  int o0 = ot * 64, p0 = pt * 128;

  __shared__ unsigned short xnT[128 * 40];
  __shared__ float sq[2][128];
  __shared__ float rl[128];

  int t = threadIdx.x;
  int lane = t & 63, w = t >> 6;
  int lr = lane & 15, lg = lane >> 4;
  int pl = t & 127, ch = t >> 7;

  const float* xb = x + (size_t)b * 256 * 4096;
  const unsigned short* wqrow = wq_bf + (size_t)(o0 + w * 16 + lr) * 256;

  f32x4 acc[8];
  f32x4 z = {0.f, 0.f, 0.f, 0.f};
#pragma unroll
  for (int i = 0; i < 8; ++i) acc[i] = z;
  float sacc = 0.f;

  for (int c0 = 0; c0 < 256; c0 += 32) {
    __syncthreads();
#pragma unroll
    for (int i = 0; i < 8; ++i) {
      int c = ch * 16 + i * 2;
      float v0 = xb[(size_t)(c0 + c) * 4096 + p0 + pl];
      float v1 = xb[(size_t)(c0 + c + 1) * 4096 + p0 + pl];
      sacc += v0 * v0 + v1 * v1;
      *(unsigned int*)&xnT[swz40(pl, c)] = pk2(v0 * g[c0 + c], v1 * g[c0 + c + 1]);
    }
    __syncthreads();
    short8 af = mk8(wqrow + c0 + lg * 8);
#pragma unroll
    for (int pt16 = 0; pt16 < 8; ++pt16) {
      short8 bf = mk8(&xnT[swz40(pt16 * 16 + lr, lg * 8)]);
      acc[pt16] = MFMA16(af, bf, acc[pt16]);
    }
  }

  sq[ch][pl] = sacc;
  __syncthreads();
  if (t < 128) rl[t] = rsqrtf((sq[0][t] + sq[1][t]) * (1.0f / 256.0f) + 1e-12f);
  __syncthreads();

  int obase = o0 + w * 16 + lg * 4;          // multiple of 4
  if (obase < 256) {
    int isK = obase >= 128;
    int oh = obase - (isK ? 128 : 0);
    int h = oh >> 5, d0 = oh & 31;
    unsigned short* dst = (isK ? kbuf : qbuf) + ((size_t)(b * 4 + h) * 4096) * 32;
#pragma unroll
    for (int pt16 = 0; pt16 < 8; ++pt16) {
      int p = p0 + pt16 * 16 + lr;
      float rr = rl[pt16 * 16 + lr];
      unsigned int u0 = pk2(acc[pt16][0] * rr, acc[pt16][1] * rr);
      unsigned int u1 = pk2(acc[pt16][2] * rr, acc[pt16][3] * rr);
      uint2 uu = {u0, u1};
      *(uint2*)(dst + (size_t)p * 32 + d0) = uu;
    }
  } else {
    int oh = obase - 256;
    int h = oh >> 5, d0 = oh & 31;
    unsigned short* dst = vbuf + ((size_t)(b * 4 + h) * 32) * 4096;
    // sigma: swap bits 2 and 3 of the within-block index (involution)
    int sl = (lr & 3) | ((lr & 4) << 1) | ((lr & 8) >> 1);
#pragma unroll
    for (int pt16 = 0; pt16 < 8; ++pt16) {
      int pp = p0 + pt16 * 16 + sl;
      float rr = rl[pt16 * 16 + lr];
#pragma unroll
      for (int r = 0; r < 4; ++r)
        dst[(size_t)(d0 + r) * 4096 + pp] = f2bf(acc[pt16][r] * rr);
    }
  }
}

// ---------------- kernel 2: flash attention, low-issue-count variant ----------------
// grid 512 = 16 bh x 32 q-tiles of 128; 8 waves: wave w = (jhalf w>>2, wq w&3).
// lsum accumulated via ones-MFMA; shuffle only inside the rare rescale branch.
__device__ __forceinline__ void attn_tile(short8 kf0, short8 kf1, short8 vf0, short8 vf1,
                                          short8 qf0, short8 qf1, short8 onesf,
                                          const f32x16& z16, float& m, float& ms,
                                          f32x16& lsacc, f32x16& oacc) {
  const float cexp = 0.25505654427102996f;  // 32^-0.5 * log2(e)
  f32x16 s = MFMA32(kf0, qf0, z16);
  s = MFMA32(kf1, qf1, s);

  // per-lane local max over 16 values (nested fmax -> v_max3)
  float a0 = fmaxf(fmaxf(s[0], s[1]), s[2]);
  float a1 = fmaxf(fmaxf(s[3], s[4]), s[5]);
  float a2 = fmaxf(fmaxf(s[6], s[7]), s[8]);
  float a3 = fmaxf(fmaxf(s[9], s[10]), s[11]);
  float a4 = fmaxf(fmaxf(s[12], s[13]), s[14]);
  float b0 = fmaxf(fmaxf(a0, a1), a2);
  float b1 = fmaxf(fmaxf(a3, a4), s[15]);
  float plmax = fmaxf(b0, b1);

  // defer-max: shared-ms update (with cross-half shuffle) only when needed.
  if (!__all(fmaf(plmax, cexp, -ms) <= 8.0f)) {
    float pmax = redmax32(plmax);           // keep ms identical across lane pair
    float mn = fmaxf(m, pmax);
    float fac = __builtin_amdgcn_exp2f((m - mn) * cexp);
    m = mn;
    ms = mn * cexp;
#pragma unroll
    for (int i = 0; i < 16; ++i) { oacc[i] *= fac; lsacc[i] *= fac; }
  }

  float p[16];
#pragma unroll
  for (int i = 0; i < 16; ++i) p[i] = __builtin_amdgcn_exp2f(fmaf(s[i], cexp, -ms));

  // Own-lane B-fragments (fast RN pack); V stored sigma-permuted to match
  uint4v u0 = {pk2rn(p[0], p[1]), pk2rn(p[2], p[3]), pk2rn(p[4], p[5]), pk2rn(p[6], p[7])};
  uint4v u1 = {pk2rn(p[8], p[9]), pk2rn(p[10], p[11]), pk2rn(p[12], p[13]), pk2rn(p[14], p[15])};
  short8 pf0 = __builtin_bit_cast(short8, u0);
  short8 pf1 = __builtin_bit_cast(short8, u1);

  lsacc = MFMA32(onesf, pf0, lsacc);   // row-sums of rounded P (layout-proof A=ones)
  lsacc = MFMA32(onesf, pf1, lsacc);
  oacc = MFMA32(vf0, pf0, oacc);
  oacc = MFMA32(vf1, pf1, oacc);
}

__global__ __launch_bounds__(512) void k_attn(const unsigned short* __restrict__ qbuf,
                                              const unsigned short* __restrict__ kbuf,
                                              const unsigned short* __restrict__ vbuf,
                                              unsigned short* __restrict__ attno) {
  __shared__ float Ol[4][16][64];   // partner O partials
  __shared__ float Ml[4][2][64];    // partner m / lsum

  int bid = blockIdx.x;
  int wid = ((bid & 7) << 6) | (bid >> 3);   // XCD-contiguous (512 % 8 == 0)
  int qt = wid & 31, bh = wid >> 5;
  int t = threadIdx.x, lane = t & 63, w = t >> 6;
  int wq = w & 3, jh = w >> 2;
  int l31 = lane & 31, hi = lane >> 5;
  const float cexp = 0.25505654427102996f;

  const unsigned short* qg = qbuf + (size_t)bh * 4096 * 32;
  const unsigned short* kg = kbuf + (size_t)bh * 4096 * 32;
  const unsigned short* vg = vbuf + (size_t)bh * 32 * 4096;

  int qrow = qt * 128 + wq * 32 + l31;
  short8 qf0 = mk8(qg + (size_t)qrow * 32 + hi * 8);
  short8 qf1 = mk8(qg + (size_t)qrow * 32 + 16 + hi * 8);

  unsigned int one2 = 0x3F803F80u;           // bf16(1.0) x2
  uint4v ov = {one2, one2, one2, one2};
  short8 onesf = __builtin_bit_cast(short8, ov);

  const f32x16 z16 = zero16();
  f32x16 oacc = zero16();
  f32x16 lsacc = zero16();
  float m = -1e30f, ms = -2.55e29f;

  int jbase = jh * 2048;
  const unsigned short* kp = kg + (size_t)(jbase + l31) * 32 + hi * 8;
  const unsigned short* vp = vg + (size_t)l31 * 4096 + hi * 8 + jbase;

  short8 kf0a = mk8(kp), kf1a = mk8(kp + 16);
  short8 vf0a = mk8(vp), vf1a = mk8(vp + 16);
  kp += 32 * 32;
  vp += 32;
  short8 kf0b, kf1b, vf0b, vf1b;

  for (int it = 0; it < 32; ++it) {          // 32 iters x 64 j
    kf0b = mk8(kp);
    kf1b = mk8(kp + 16);
    vf0b = mk8(vp);
    vf1b = mk8(vp + 16);
    kp += 1024;
    vp += 32;
    attn_tile(kf0a, kf1a, vf0a, vf1a, qf0, qf1, onesf, z16, m, ms, lsacc, oacc);

    kf0a = mk8(kp);                          // last iter: dead prefetch (mapped ws)
    kf1a = mk8(kp + 16);
    vf0a = mk8(vp);
    vf1a = mk8(vp + 16);
    kp += 1024;
    vp += 32;
    attn_tile(kf0b, kf1b, vf0b, vf1b, qf0, qf1, onesf, z16, m, ms, lsacc, oacc);
  }

  float lsum = lsacc[0];   // pair-shared row total for q = l31, this j-half

  if (jh == 1) {
#pragma unroll
    for (int i = 0; i < 16; ++i) Ol[wq][i][lane] = oacc[i];
    Ml[wq][0][lane] = m;
    Ml[wq][1][lane] = lsum;
  }
  __syncthreads();
  if (jh == 0) {
    float mb = Ml[wq][0][lane], lb = Ml[wq][1][lane];
    float M = fmaxf(m, mb);
    float fa = __builtin_amdgcn_exp2f((m - M) * cexp);
    float fb = __builtin_amdgcn_exp2f((mb - M) * cexp);
    float rinv = 1.0f / (lsum * fa + lb * fb);
    fa *= rinv;
    fb *= rinv;

    int b = bh >> 2, h = bh & 3;
    unsigned short* ob = attno + ((size_t)b * 4096 + qrow) * 128 + h * 32;
#pragma unroll
    for (int r2 = 0; r2 < 8; ++r2) {
      int reg = r2 * 2;
      int dv = (reg & 3) + 8 * (reg >> 2) + 4 * hi;
      float v0 = oacc[reg] * fa + Ol[wq][reg][lane] * fb;
      float v1 = oacc[reg + 1] * fa + Ol[wq][reg + 1][lane] * fb;
      *(unsigned int*)(ob + dv) = pk2(v0, v1);
    }
  }
}

// ---------------- kernel 3: output projection + bias ----------------
__global__ __launch_bounds__(256) void k_out(const unsigned short* __restrict__ attno,
                                             const unsigned short* __restrict__ wo_bf,
                                             const float* __restrict__ bo,
                                             float* __restrict__ out) {
  int bid = blockIdx.x;
  int b = bid >> 6;
  int p0 = (bid & 63) * 64;
  int t = threadIdx.x, lane = t & 63, w = t >> 6;
  int lr = lane & 15, lg = lane >> 4;

  f32x4 z = {0.f, 0.f, 0.f, 0.f};
  f32x4 acc[4][4];
#pragma unroll
  for (int i = 0; i < 4; ++i)
#pragma unroll
    for (int j = 0; j < 4; ++j) acc[i][j] = z;

  for (int c0 = 0; c0 < 128; c0 += 32) {
    short8 bfr[4];
#pragma unroll
    for (int pt16 = 0; pt16 < 4; ++pt16)
      bfr[pt16] = mk8(attno + (size_t)(b * 4096 + p0 + pt16 * 16 + lr) * 128 + c0 + lg * 8);
#pragma unroll
    for (int ct = 0; ct < 4; ++ct) {
      short8 afr = mk8(wo_bf + (size_t)(w * 64 + ct * 16 + lr) * 128 + c0 + lg * 8);
#pragma unroll
      for (int pt16 = 0; pt16 < 4; ++pt16)
        acc[ct][pt16] = MFMA16(afr, bfr[pt16], acc[ct][pt16]);
    }
  }

#pragma unroll
  for (int ct = 0; ct < 4; ++ct) {
#pragma unroll
    for (int pt16 = 0; pt16 < 4; ++pt16) {
#pragma unroll
      for (int r = 0; r < 4; ++r) {
        int co = w * 64 + ct * 16 + lg * 4 + r;
        int p = p0 + pt16 * 16 + lr;
        out[((size_t)b * 256 + co) * 4096 + p] = acc[ct][pt16][r] + bo[co];
      }
    }
  }
}

extern "C" void kernel_launch(void* const* d_in, const int* in_sizes, int n_in,
                              void* d_out, int out_size, void* d_ws, size_t ws_size,
                              hipStream_t stream) {
  const float* x = (const float*)d_in[0];
  const float* g = (const float*)d_in[1];
  const float* wq = (const float*)d_in[2];
  const float* wo = (const float*)d_in[3];
  const float* bo = (const float*)d_in[4];
  float* out = (float*)d_out;

  char* ws = (char*)d_ws;
  unsigned short* wq_bf = (unsigned short*)(ws + 65536);     // 196608 B
  unsigned short* wo_bf = (unsigned short*)(ws + 262144);    // 65536 B
  unsigned short* qbuf = (unsigned short*)(ws + 327680);     // 4 MiB
  unsigned short* kbuf = (unsigned short*)(ws + 4521984);    // 4 MiB
  unsigned short* vbuf = (unsigned short*)(ws + 8716288);    // 4 MiB
  unsigned short* attno = (unsigned short*)(ws + 12910592);  // 4 MiB

  k_prep<<<dim3(384), dim3(256), 0, stream>>>(wq, wo, wq_bf, wo_bf);
  k_qkv<<<dim3(768), dim3(256), 0, stream>>>(x, g, wq_bf, qbuf, kbuf, vbuf);
  k_attn<<<dim3(512), dim3(512), 0, stream>>>(qbuf, kbuf, vbuf, attno);
  k_out<<<dim3(256), dim3(256), 0, stream>>>(attno, wo_bf, bo, out);
}